// Round 6
// baseline (243.981 us; speedup 1.0000x reference)
//
#include <hip/hip_runtime.h>
#include <cstddef>

// Problem constants
// B=8, DIM=256, NH=8, H=W=56, G=4, CG=64, GH=2, HC=32, Hk=Wk=8, ns=64

typedef short bf16x8 __attribute__((ext_vector_type(8)));
typedef float f32x4 __attribute__((ext_vector_type(4)));

static __device__ __forceinline__ ushort f2bf(float f) {
  union { float f; unsigned u; } v; v.f = f;
  unsigned r = v.u + 0x7fffu + ((v.u >> 16) & 1u);   // RNE
  return (ushort)(r >> 16);
}
static __device__ __forceinline__ float bf2f(ushort u) {
  union { unsigned u; float f; } v; v.u = ((unsigned)u) << 16;
  return v.f;
}

// ws float offsets
#define OFF_FEATB 0u          // feat bf16 [b*3136+m][256c] (later reused as attnpk)
#define OFF_QPK   3211264u    // q bf16 [b*3136+m][256c]
#define OFF_Q     6422528u    // q fp32 [b][c][m]; ALSO aliased as xb bf16 (earlier)
#define OFF_POS   12845056u   // 4096
#define OFF_XS    12849152u   // 131072 (offset-conv scratch)
#define OFF_KPK   12980224u   // K bf16 pack [b][h][c8=4][n=64][8]
#define OFF_VPK   13045760u   // V bf16 pack [b][h][n8=8][c=32][8]
#define OFF_PWP   13111296u   // pw pack 49152 bf16
#define OFF_WQP   13135872u   // 65536 bf16
#define OFF_WOP   13168640u   // 65536 bf16
#define OFF_WKT   13201408u   // 65536 fl
#define OFF_WVT   13266944u   // 65536 fl -> end 13332480 fl (53.3 MB)

// ---------------------------------------------------------------------------
// Kernel X: convert x fp32 -> bf16 (same layout).  4816896 elements.
__global__ __launch_bounds__(256) void k_xcvt(
    const float* __restrict__ x, ushort* __restrict__ xb) {
  const size_t i0 = ((size_t)blockIdx.x * 256 + threadIdx.x) * 8;
  float4 v0 = *(const float4*)(x + i0);
  float4 v1 = *(const float4*)(x + i0 + 4);
  bf16x8 o;
  o[0] = (short)f2bf(v0.x); o[1] = (short)f2bf(v0.y);
  o[2] = (short)f2bf(v0.z); o[3] = (short)f2bf(v0.w);
  o[4] = (short)f2bf(v1.x); o[5] = (short)f2bf(v1.y);
  o[6] = (short)f2bf(v1.z); o[7] = (short)f2bf(v1.w);
  *(bf16x8*)(xb + i0) = o;
}

// ---------------------------------------------------------------------------
// Kernel P: pack weights.
__global__ __launch_bounds__(256) void k_pack(
    const float* __restrict__ pw, const float* __restrict__ wq,
    const float* __restrict__ wk, const float* __restrict__ wv,
    const float* __restrict__ wo, ushort* __restrict__ pwp,
    ushort* __restrict__ wqp, ushort* __restrict__ wop,
    float* __restrict__ wkT, float* __restrict__ wvT) {
  const int o = blockIdx.x, t = threadIdx.x, m = blockIdx.y;
  if (m == 0) {
    if (t < 192) pwp[((t >> 3) * 256 + o) * 8 + (t & 7)] = f2bf(pw[o * 192 + t]);
  } else if (m == 1) {
    wqp[((t >> 3) * 256 + o) * 8 + (t & 7)] = f2bf(wq[o * 256 + t]);
  } else if (m == 2) {
    wop[((t >> 3) * 256 + o) * 8 + (t & 7)] = f2bf(wo[o * 256 + t]);
  } else if (m == 3) {
    wkT[t * 256 + o] = wk[o * 256 + t];
  } else {
    wvT[t * 256 + o] = wv[o * 256 + t];
  }
}

// ---------------------------------------------------------------------------
// Kernel A: patch conv (im2col MFMA, K=192) + bias + channel-LN -> bf16 [m][c]
__global__ __launch_bounds__(256) void k_patch_mfma(
    const ushort* __restrict__ xb, const ushort* __restrict__ pwp,
    const float* __restrict__ pb, const float* __restrict__ g1,
    const float* __restrict__ b1, ushort* __restrict__ featb) {
  const int t = threadIdx.x;
  const int lane = t & 63;
  const int wid = t >> 6;
  const int m_base = blockIdx.x * 64 + wid * 16;
  const int kg = lane >> 4;
  const int lr = lane & 15;
  const int mA = m_base + lr;
  const int bA = mA / 3136;
  const int posA = mA - bA * 3136;
  const int ohA = posA / 56;
  const int owA = posA - ohA * 56;

  f32x4 acc[16];
#pragma unroll
  for (int f = 0; f < 16; f++) {
    float bv = pb[f * 16 + lr];
    acc[f] = (f32x4){bv, bv, bv, bv};
  }
#pragma unroll
  for (int ks = 0; ks < 6; ks++) {
    const int k8 = ks * 4 + kg;
    const int ci = k8 >> 3, ii = k8 & 7;
    bf16x8 a = *(const bf16x8*)(xb +
        (((size_t)bA * 3 + ci) * 448 + (ohA * 8 + ii)) * 448 + owA * 8);
#pragma unroll
    for (int f = 0; f < 16; f++) {
      bf16x8 bfr = *(const bf16x8*)(pwp + (size_t)(k8 * 256 + f * 16 + lr) * 8);
      acc[f] = __builtin_amdgcn_mfma_f32_16x16x32_bf16(a, bfr, acc[f], 0, 0, 0);
    }
  }
  float mean[4], rstd[4];
#pragma unroll
  for (int j = 0; j < 4; j++) {
    float s1 = 0.f, s2 = 0.f;
#pragma unroll
    for (int f = 0; f < 16; f++) { float v = acc[f][j]; s1 += v; s2 += v * v; }
#pragma unroll
    for (int off = 8; off >= 1; off >>= 1) {
      s1 += __shfl_xor(s1, off);
      s2 += __shfl_xor(s2, off);
    }
    float mn = s1 * (1.f / 256.f);
    float var = s2 * (1.f / 256.f) - mn * mn;
    mean[j] = mn; rstd[j] = rsqrtf(var + 1e-5f);
  }
#pragma unroll
  for (int f = 0; f < 16; f++) {
    const int c = f * 16 + lr;
    const float gg = g1[c], bb = b1[c];
#pragma unroll
    for (int j = 0; j < 4; j++) {
      const int mo = m_base + kg * 4 + j;
      float v = (acc[f][j] - mean[j]) * rstd[j] * gg + bb;
      featb[(size_t)mo * 256 + c] = f2bf(v);
    }
  }
}

// ---------------------------------------------------------------------------
// Kernel B: MFMA GEMM: out fp32 [b][o][m]; optional bf16 [m][o] pack (opk).
__global__ __launch_bounds__(512) void k_gemm_mfma(
    const ushort* __restrict__ apk, const ushort* __restrict__ wp,
    const float* __restrict__ bias, float* __restrict__ out,
    ushort* __restrict__ opk) {
  const int t = threadIdx.x;
  const int lane = t & 63;
  const int wid = t >> 6;
  const int mt = wid >> 1, nh = wid & 1;
  const int lr = lane & 15, kg = lane >> 4;
  const int m_base = blockIdx.x * 64 + mt * 16;
  const int mA = m_base + lr;

  f32x4 acc[8];
#pragma unroll
  for (int f = 0; f < 8; f++) {
    float bv = bias[nh * 128 + f * 16 + lr];
    acc[f] = (f32x4){bv, bv, bv, bv};
  }
  const ushort* arow = apk + (size_t)mA * 256;
#pragma unroll
  for (int ks = 0; ks < 8; ks++) {
    bf16x8 a = *(const bf16x8*)(arow + ks * 32 + kg * 8);
#pragma unroll
    for (int f = 0; f < 8; f++) {
      const int o = nh * 128 + f * 16 + lr;
      bf16x8 bfr = *(const bf16x8*)(wp + (size_t)((ks * 4 + kg) * 256 + o) * 8);
      acc[f] = __builtin_amdgcn_mfma_f32_16x16x32_bf16(a, bfr, acc[f], 0, 0, 0);
    }
  }
  __shared__ float sA[64 * 257];
#pragma unroll
  for (int f = 0; f < 8; f++) {
#pragma unroll
    for (int j = 0; j < 4; j++)
      sA[(mt * 16 + kg * 4 + j) * 257 + nh * 128 + f * 16 + lr] = acc[f][j];
  }
  __syncthreads();
  const int b = (blockIdx.x * 64) / 3136;
  const int pos0 = (blockIdx.x * 64) % 3136;
#pragma unroll
  for (int i = 0; i < 32; i++) {
    int idx = t + i * 512;
    int c = idx >> 6, mm = idx & 63;
    out[((size_t)b * 256 + c) * 3136 + pos0 + mm] = sA[mm * 257 + c];
  }
  if (opk) {
    const int mm = t & 63;
    const int cs = t >> 6;   // 0..7
#pragma unroll
    for (int i = 0; i < 4; i++) {
      int c0 = cs * 32 + i * 8;
      bf16x8 v8;
#pragma unroll
      for (int j = 0; j < 8; j++) v8[j] = (short)f2bf(sA[mm * 257 + c0 + j]);
      *(bf16x8*)(opk + ((size_t)(blockIdx.x * 64 + mm)) * 256 + c0) = v8;
    }
  }
}

// ---------------------------------------------------------------------------
// Kernel C1: offset depthwise conv (28x28, stride 8, pad 14).
__global__ __launch_bounds__(128) void k_offset_conv(
    const float* __restrict__ q, const float* __restrict__ dww,
    float* __restrict__ convo) {
  const int bg = blockIdx.y;
  const int wv = threadIdx.x >> 6;
  const int lane = threadIdx.x & 63;
  const int ch = blockIdx.x * 2 + wv;
  const int b = bg >> 2, g = bg & 3;

  __shared__ float pl[2][7072];
  float* P = pl[wv];
  for (int idx = lane; idx < 7072; idx += 64) P[idx] = 0.f;

  const float* qb = q + ((size_t)b * 256 + g * 64 + ch) * 3136;
  if (lane < 56) {
    for (int r = 0; r < 56; r++) {
      int hr = r + 14;
      P[hr * 84 + (lane + 14) + (hr >> 3)] = qb[r * 56 + lane];
    }
  }
  const int oh = lane >> 3, ow = lane & 7;
  const int chs = __builtin_amdgcn_readfirstlane(ch);
  const float* wr = dww + (size_t)chs * 784;
  float acc = 0.f;
  const int r0 = oh * 8, c0 = ow * 8;
  for (int i = 0; i < 28; i++) {
    int hr = r0 + i;
    const float* prow = P + hr * 84 + c0 + (hr >> 3);
    const float* wrr = wr + i * 28;
#pragma unroll
    for (int j = 0; j < 28; j++)
      acc = fmaf(prow[j], wrr[j], acc);
  }
  convo[bg * 4096 + lane * 64 + ch] = acc;
}

// ---------------------------------------------------------------------------
// Kernel C2: LN(64) + GELU + pointwise(2x64) + tanh + reference points.
__global__ __launch_bounds__(256) void k_offset_post(
    const float* __restrict__ convo, const float* __restrict__ dwb,
    const float* __restrict__ lng, const float* __restrict__ lnb,
    const float* __restrict__ pww, float* __restrict__ pos_ws,
    float* __restrict__ out_pos, float* __restrict__ out_ref) {
  const int bg = blockIdx.y;
  const int wv = threadIdx.x >> 6;
  const int lane = threadIdx.x & 63;
  const int idx = blockIdx.x * 4 + wv;
  const int oh = idx >> 3, ow = idx & 7;

  float acc = convo[bg * 4096 + idx * 64 + lane] + dwb[lane];

  float s1 = acc, s2 = acc * acc;
#pragma unroll
  for (int off = 32; off >= 1; off >>= 1) {
    s1 += __shfl_xor(s1, off);
    s2 += __shfl_xor(s2, off);
  }
  float m = s1 * (1.f / 64.f);
  float var = s2 * (1.f / 64.f) - m * m;
  float val = (acc - m) * rsqrtf(var + 1e-5f) * lng[lane] + lnb[lane];
  val = 0.5f * val * (1.f + erff(val * 0.70710678118654752f));
  float p0 = pww[lane] * val, p1 = pww[64 + lane] * val;
#pragma unroll
  for (int off = 32; off >= 1; off >>= 1) {
    p0 += __shfl_xor(p0, off);
    p1 += __shfl_xor(p1, off);
  }
  if (lane == 0) {
    float offy = tanhf(p0) * (2.0f / 7.0f);
    float offx = tanhf(p1) * (2.0f / 7.0f);
    float ry = (0.5f + oh) * (2.0f / 7.0f) - 1.0f;
    float rx = (0.5f + ow) * (2.0f / 7.0f) - 1.0f;
    float py = offy + ry, px = offx + rx;
    int o = bg * 128 + idx * 2;
    pos_ws[o] = py;  pos_ws[o + 1] = px;
    out_pos[o] = py; out_pos[o + 1] = px;
    out_ref[o] = ry; out_ref[o + 1] = rx;
  }
}

// ---------------------------------------------------------------------------
// Kernel DE: fused bilinear sampling + k,v projections -> bf16 B-frag packs.
// Block (n, b): phase 1 wave g samples 64 channels of group g at point n;
// phase 2 = 256x256 kv GEMV on the sampled vector.
__global__ __launch_bounds__(256) void k_sample_kv(
    const ushort* __restrict__ featb, const float* __restrict__ pos_ws,
    const float* __restrict__ wkT, const float* __restrict__ bk,
    const float* __restrict__ wvT, const float* __restrict__ bv,
    ushort* __restrict__ kpk, ushort* __restrict__ vpk) {
  const int b = blockIdx.y;   // 0..7
  const int n = blockIdx.x;   // 0..63
  const int t = threadIdx.x;
  const int g = t >> 6, lane = t & 63;
  const int bg = b * 4 + g;

  __shared__ float sxs[256];
  {
    float py = pos_ws[bg * 128 + n * 2];
    float px = pos_ws[bg * 128 + n * 2 + 1];
    float gx = (px + 1.f) * 0.5f * 55.f;
    float gy = (py + 1.f) * 0.5f * 55.f;
    float x0f = floorf(gx), y0f = floorf(gy);
    int x0 = (int)x0f, y0 = (int)y0f;
    float wx1 = gx - x0f, wx0 = 1.f - wx1;
    float wy1 = gy - y0f, wy0 = 1.f - wy1;
    const size_t mb = (size_t)b * 3136;
    const int cofs = g * 64 + lane;
    float acc = 0.f;
    if (x0 >= 0 && x0 <= 55 && y0 >= 0 && y0 <= 55)
      acc = fmaf(bf2f(featb[(mb + y0 * 56 + x0) * 256 + cofs]), wx0 * wy0, acc);
    if (x0 + 1 >= 0 && x0 + 1 <= 55 && y0 >= 0 && y0 <= 55)
      acc = fmaf(bf2f(featb[(mb + y0 * 56 + x0 + 1) * 256 + cofs]), wx1 * wy0, acc);
    if (x0 >= 0 && x0 <= 55 && y0 + 1 >= 0 && y0 + 1 <= 55)
      acc = fmaf(bf2f(featb[(mb + (y0 + 1) * 56 + x0) * 256 + cofs]), wx0 * wy1, acc);
    if (x0 + 1 >= 0 && x0 + 1 <= 55 && y0 + 1 >= 0 && y0 + 1 <= 55)
      acc = fmaf(bf2f(featb[(mb + (y0 + 1) * 56 + x0 + 1) * 256 + cofs]), wx1 * wy1, acc);
    sxs[g * 64 + lane] = acc;
  }
  __syncthreads();

  float ak = bk[t], av = bv[t];
  for (int c = 0; c < 256; c++) {
    float xv = sxs[c];
    ak = fmaf(wkT[c * 256 + t], xv, ak);
    av = fmaf(wvT[c * 256 + t], xv, av);
  }
  const int h = t >> 5, cc = t & 31;
  const size_t base = (size_t)(b * 8 + h) * 2048;
  kpk[base + (size_t)((cc >> 3) * 64 + n) * 8 + (cc & 7)] = f2bf(ak);
  vpk[base + (size_t)((n >> 3) * 32 + cc) * 8 + (n & 7)] = f2bf(av);
}

// ---------------------------------------------------------------------------
// Kernel F: MFMA attention. Block = (b, g, 64-query tile); 4 waves x 16 q.
// Bias MLP computed per thread, in C-fragment layout (registers, no LDS).
__global__ __launch_bounds__(256) void k_attn_mfma(
    const ushort* __restrict__ qpk, const ushort* __restrict__ kpk,
    const ushort* __restrict__ vpk, const float* __restrict__ pos_ws,
    const float* __restrict__ w1, const float* __restrict__ b1,
    const float* __restrict__ w2, ushort* __restrict__ attnpk) {
  const int bg = blockIdx.y;           // b*4+g
  const int b = bg >> 2, g = bg & 3;
  const int m0 = blockIdx.x * 64;
  const int t = threadIdx.x;
  const int lane = t & 63, w = t >> 6;
  const int lr = lane & 15, kg = lane >> 4;

  __shared__ ushort Pbuf[4][16 * 72];  // per-wave P staging
  __shared__ ushort outb[64 * 72];     // epilogue tile (64 rows x 64c + pad)
  __shared__ float posl[128];
  __shared__ float4 rpe4[32];          // {w1y, w1x, b1, w2[0]}
  __shared__ float rpeB[32];           // w2[1]

  if (t < 128) posl[t] = pos_ws[bg * 128 + t];
  if (t < 32) {
    rpe4[t] = make_float4(w1[t * 2], w1[t * 2 + 1], b1[t], w2[t]);
    rpeB[t] = w2[32 + t];
  }
  __syncthreads();

  // --- bias MLP in registers, C-layout: pair p = nf*4+j ->
  //     row r = w*16+kg*4+j (query m0+r), col = nf*16+lr (point n)
  float qgy[4], qgx[4];
#pragma unroll
  for (int j = 0; j < 4; j++) {
    int m = m0 + w * 16 + kg * 4 + j;
    int my = m / 56, mx = m % 56;
    qgy[j] = (float)my * (56.0f / 55.0f) * (2.0f / 55.0f) - 1.0f;
    qgx[j] = (float)mx * (56.0f / 55.0f) * (2.0f / 55.0f) - 1.0f;
  }
  float tyv[16], txv[16];
#pragma unroll
  for (int nf = 0; nf < 4; nf++) {
    int n = nf * 16 + lr;
    float py = posl[2 * n], px = posl[2 * n + 1];
#pragma unroll
    for (int j = 0; j < 4; j++) {
      float dy = (qgy[j] - py) * 4.f;
      float dx = (qgx[j] - px) * 4.f;
      tyv[nf * 4 + j] = copysignf(__log2f(fabsf(dy) + 1.f) * (1.f / 3.f), dy);
      txv[nf * 4 + j] = copysignf(__log2f(fabsf(dx) + 1.f) * (1.f / 3.f), dx);
    }
  }
  float bb0[16], bb1[16];
#pragma unroll
  for (int p = 0; p < 16; p++) { bb0[p] = 0.f; bb1[p] = 0.f; }
  for (int jj = 0; jj < 32; jj++) {
    float4 r = rpe4[jj];
    float wb = rpeB[jj];
#pragma unroll
    for (int p = 0; p < 16; p++) {
      float hv = fmaxf(fmaf(r.x, tyv[p], fmaf(r.y, txv[p], r.z)), 0.f);
      bb0[p] = fmaf(r.w, hv, bb0[p]);
      bb1[p] = fmaf(wb, hv, bb1[p]);
    }
  }

  const int mrow = m0 + w * 16 + lr;
  const float scale = 0.17677669529663687f;   // 1/sqrt(32)
  ushort* pb = Pbuf[w];

  f32x4 oacc[2][2];
#pragma unroll
  for (int gh = 0; gh < 2; gh++)
#pragma unroll
    for (int cf = 0; cf < 2; cf++) oacc[gh][cf] = (f32x4){0.f, 0.f, 0.f, 0.f};

#pragma unroll
  for (int gh = 0; gh < 2; gh++) {
    // S = Q K^T  (K=32 contraction -> one mfma per 16-col frag)
    bf16x8 a = *(const bf16x8*)(qpk +
        ((size_t)(b * 3136 + mrow) * 256 + g * 64 + gh * 32 + kg * 8));
    const ushort* kbase = kpk + (size_t)(b * 8 + g * 2 + gh) * 2048;
    f32x4 s[4];
#pragma unroll
    for (int nf = 0; nf < 4; nf++) {
      bf16x8 bfr = *(const bf16x8*)(kbase + (size_t)(kg * 64 + nf * 16 + lr) * 8);
      s[nf] = __builtin_amdgcn_mfma_f32_16x16x32_bf16(
          a, bfr, (f32x4){0.f, 0.f, 0.f, 0.f}, 0, 0, 0);
    }
    // scale + bias (registers, C-layout)
#pragma unroll
    for (int nf = 0; nf < 4; nf++)
#pragma unroll
      for (int j = 0; j < 4; j++)
        s[nf][j] = fmaf(s[nf][j], scale,
                        gh ? bb1[nf * 4 + j] : bb0[nf * 4 + j]);
    // softmax over n (4 frags x 16 lr-lanes)
#pragma unroll
    for (int j = 0; j < 4; j++) {
      float m1 = fmaxf(fmaxf(s[0][j], s[1][j]), fmaxf(s[2][j], s[3][j]));
#pragma unroll
      for (int o = 8; o >= 1; o >>= 1) m1 = fmaxf(m1, __shfl_xor(m1, o));
      float ss = 0.f;
#pragma unroll
      for (int nf = 0; nf < 4; nf++) {
        float e = __expf(s[nf][j] - m1);
        s[nf][j] = e;
        ss += e;
      }
#pragma unroll
      for (int o = 8; o >= 1; o >>= 1) ss += __shfl_xor(ss, o);
      float inv = 1.f / ss;
#pragma unroll
      for (int nf = 0; nf < 4; nf++) s[nf][j] *= inv;
    }
    // P -> wave-private LDS [16 rows][72]
#pragma unroll
    for (int nf = 0; nf < 4; nf++)
#pragma unroll
      for (int j = 0; j < 4; j++)
        pb[(kg * 4 + j) * 72 + nf * 16 + lr] = f2bf(s[nf][j]);
    // PV: out[i][c] += P[i][n] V[n][c]
    const ushort* vbase = vpk + (size_t)(b * 8 + g * 2 + gh) * 2048;
#pragma unroll
    for (int ks = 0; ks < 2; ks++) {
      bf16x8 pa = *(const bf16x8*)(pb + lr * 72 + ks * 32 + kg * 8);
#pragma unroll
      for (int cf = 0; cf < 2; cf++) {
        bf16x8 vb = *(const bf16x8*)(vbase +
            (size_t)((ks * 4 + kg) * 32 + cf * 16 + lr) * 8);
        oacc[gh][cf] = __builtin_amdgcn_mfma_f32_16x16x32_bf16(
            pa, vb, oacc[gh][cf], 0, 0, 0);
      }
    }
  }

  // out tile (wave-private rows, stride 72 ushorts = 144B)
#pragma unroll
  for (int gh = 0; gh < 2; gh++)
#pragma unroll
    for (int cf = 0; cf < 2; cf++)
#pragma unroll
      for (int j = 0; j < 4; j++)
        outb[(w * 16 + kg * 4 + j) * 72 + gh * 32 + cf * 16 + lr] =
            f2bf(oacc[gh][cf][j]);
  __syncthreads();
  // coalesced store: 64 rows x 64 c (this group's 64 channels)
#pragma unroll
  for (int r2 = 0; r2 < 2; r2++) {
    int row = (t >> 3) + r2 * 32;
    int chunk = t & 7;
    bf16x8 v8 = *(const bf16x8*)(outb + row * 72 + chunk * 8);
    *(bf16x8*)(attnpk +
               ((size_t)(b * 3136 + m0 + row) * 256 + g * 64 + chunk * 8)) = v8;
  }
}

// ---------------------------------------------------------------------------
extern "C" void kernel_launch(void* const* d_in, const int* in_sizes, int n_in,
                              void* d_out, int out_size, void* d_ws,
                              size_t ws_size, hipStream_t stream) {
  const float* x       = (const float*)d_in[0];
  const float* patch_w = (const float*)d_in[1];
  const float* patch_b = (const float*)d_in[2];
  const float* ln1_g   = (const float*)d_in[3];
  const float* ln1_b   = (const float*)d_in[4];
  const float* wq      = (const float*)d_in[5];
  const float* bq      = (const float*)d_in[6];
  const float* wk      = (const float*)d_in[7];
  const float* bk      = (const float*)d_in[8];
  const float* wv      = (const float*)d_in[9];
  const float* bv      = (const float*)d_in[10];
  const float* wo      = (const float*)d_in[11];
  const float* bo      = (const float*)d_in[12];
  const float* off_dw_w = (const float*)d_in[13];
  const float* off_dw_b = (const float*)d_in[14];
  const float* off_ln_g = (const float*)d_in[15];
  const float* off_ln_b = (const float*)d_in[16];
  const float* off_pw_w = (const float*)d_in[17];
  const float* rpe_w1  = (const float*)d_in[18];
  const float* rpe_b1  = (const float*)d_in[19];
  const float* rpe_w2  = (const float*)d_in[20];

  float* ws = (float*)d_ws;
  ushort* featb = (ushort*)(ws + OFF_FEATB);   // bf16 [m][c]
  ushort* attnpk = featb;                      // reuse (feat dead after sample)
  ushort* qpk = (ushort*)(ws + OFF_QPK);       // bf16 [m][c]
  float* q    = ws + OFF_Q;                    // fp32 [c][m]
  ushort* xb  = (ushort*)(ws + OFF_Q);         // bf16 x (dead before q written)
  float* posw = ws + OFF_POS;
  float* convo = ws + OFF_XS;
  ushort* kpk = (ushort*)(ws + OFF_KPK);
  ushort* vpk = (ushort*)(ws + OFF_VPK);
  ushort* pwp = (ushort*)(ws + OFF_PWP);
  ushort* wqp = (ushort*)(ws + OFF_WQP);
  ushort* wop = (ushort*)(ws + OFF_WOP);
  float* wkT  = ws + OFF_WKT;
  float* wvT  = ws + OFF_WVT;

  float* y = (float*)d_out;
  float* out_pos = y + 6422528;
  float* out_ref = out_pos + 4096;

  // X: x -> bf16 (4816896 elems = 2352 * 2048)
  hipLaunchKernelGGL(k_xcvt, dim3(2352), dim3(256), 0, stream, x, xb);
  // P: weight packs / transposes
  hipLaunchKernelGGL(k_pack, dim3(256, 5), dim3(256), 0, stream,
                     patch_w, wq, wk, wv, wo, pwp, wqp, wop, wkT, wvT);
  // A: patch embed conv (MFMA) + LN -> feat bf16 [m][c]
  hipLaunchKernelGGL(k_patch_mfma, dim3(392), dim3(256), 0, stream,
                     xb, pwp, patch_b, ln1_g, ln1_b, featb);
  // B: q = wq @ feat + bq  -> fp32 [c][m] + bf16 pack [m][c]
  hipLaunchKernelGGL(k_gemm_mfma, dim3(392), dim3(512), 0, stream,
                     featb, wqp, bq, q, qpk);
  // C1: offset depthwise conv
  hipLaunchKernelGGL(k_offset_conv, dim3(32, 32), dim3(128), 0, stream,
                     q, off_dw_w, convo);
  // C2: offset post (LN + GELU + pointwise + tanh) -> pos
  hipLaunchKernelGGL(k_offset_post, dim3(16, 32), dim3(256), 0, stream,
                     convo, off_dw_b, off_ln_g, off_ln_b, off_pw_w,
                     posw, out_pos, out_ref);
  // DE: fused sampling + k,v projections -> bf16 B-frag packs
  hipLaunchKernelGGL(k_sample_kv, dim3(64, 8), dim3(256), 0, stream,
                     featb, posw, wkT, bk, wvT, bv, kpk, vpk);
  // F: MFMA attention -> bf16 pack [m][c]
  hipLaunchKernelGGL(k_attn_mfma, dim3(49, 32), dim3(256), 0, stream,
                     qpk, kpk, vpk, posw, rpe_w1, rpe_b1, rpe_w2, attnpk);
  // G: y = wo @ attn_out + bo  (fp32 [c][m] = d_out)
  hipLaunchKernelGGL(k_gemm_mfma, dim3(392), dim3(512), 0, stream,
                     attnpk, wop, bo, y, (ushort*)nullptr);
}